// Round 17
// baseline (198.143 us; speedup 1.0000x reference)
//
#include <hip/hip_runtime.h>
#include <hip/hip_bf16.h>
#include <stdint.h>
#include <math.h>

#define B_   4
#define H_   16
#define LQ_  1024
#define LKV_ 2048
#define DM_  1024
#define DH_  64

typedef __attribute__((ext_vector_type(8))) __bf16 bf16x8;
typedef __attribute__((ext_vector_type(4))) float  f32x4;
typedef __attribute__((ext_vector_type(16))) float f32x16;
typedef __attribute__((ext_vector_type(8))) short  short8;
typedef __attribute__((ext_vector_type(2))) unsigned uint2v;

__device__ __forceinline__ void gload_lds16(const void* g, void* l) {
  __builtin_amdgcn_global_load_lds(
      (const __attribute__((address_space(1))) void*)g,
      (__attribute__((address_space(3))) void*)l, 16, 0, 0);
}

// Explicit LDS-DMA drain before publishing barrier (race-proven in R3).
__device__ __forceinline__ void drain_vmem() {
  asm volatile("s_waitcnt vmcnt(0)" ::: "memory");
  __builtin_amdgcn_sched_barrier(0);
}

// Raw v_exp_f32 (exp2): OCML exp2f has denorm fixup (R4 regression).
#if __has_builtin(__builtin_amdgcn_exp2f)
__device__ __forceinline__ float EXP2(float x) { return __builtin_amdgcn_exp2f(x); }
#else
__device__ __forceinline__ float EXP2(float x) {
  float r; asm("v_exp_f32 %0, %1" : "=v"(r) : "v"(x)); return r;
}
#endif

// a' = [a.lo32, b.lo32], b' = [a.hi32, b.hi32]
#if __has_builtin(__builtin_amdgcn_permlane32_swap)
__device__ __forceinline__ void xswap(unsigned& a, unsigned& b) {
  uint2v r = __builtin_amdgcn_permlane32_swap(a, b, false, false);
  a = r[0]; b = r[1];
}
#else
__device__ __forceinline__ void xswap(unsigned& a, unsigned& b) {
  unsigned xa = (unsigned)__shfl_xor((int)a, 32);
  unsigned xb = (unsigned)__shfl_xor((int)b, 32);
  bool hi = (threadIdx.x & 32) != 0;
  unsigned na = hi ? xb : a;
  unsigned nb = hi ? b : xa;
  a = na; b = nb;
}
#endif

__device__ __forceinline__ unsigned pack2(float a, float b) {
  unsigned lo = (unsigned)__bfloat16_as_ushort(__float2bfloat16(a));
  unsigned hi = (unsigned)__bfloat16_as_ushort(__float2bfloat16(b));
  return lo | (hi << 16);
}

// ---------------- fused fp32 -> bf16 cast ----------------
struct CastArgs {
  const float* src[6];
  __hip_bfloat16* dst[6];
  int n[6];
};

__global__ void cast_multi(CastArgs a) {
  int seg = blockIdx.y;
  int n = a.n[seg];
  int i = (blockIdx.x * blockDim.x + threadIdx.x) * 8;
  if (i >= n) return;
  const float* s = a.src[seg] + i;
  float4 x = *(const float4*)s;
  float4 y = *(const float4*)(s + 4);
  union { short8 v; __hip_bfloat16 h[8]; } u;
  u.h[0] = __float2bfloat16(x.x); u.h[1] = __float2bfloat16(x.y);
  u.h[2] = __float2bfloat16(x.z); u.h[3] = __float2bfloat16(x.w);
  u.h[4] = __float2bfloat16(y.x); u.h[5] = __float2bfloat16(y.y);
  u.h[6] = __float2bfloat16(y.z); u.h[7] = __float2bfloat16(y.w);
  *(short8*)(a.dst[seg] + i) = u.v;
}

// Multiplicative bf16 mask (1.0 / 0.0) — feeds the l-sum MFMA B-operand.
__global__ void mask_mul(const int* __restrict__ msk, __hip_bfloat16* __restrict__ mb, int n) {
  int i = blockIdx.x * blockDim.x + threadIdx.x;
  if (i < n) mb[i] = __float2bfloat16(msk[i] ? 1.0f : 0.0f);
}

// ---------------- GEMM 128x64 (O projection), XCD-bijective 1D grid (R16 proven) ----------------
template<int MODE>
__global__ __launch_bounds__(256, 3)
void gemm_bt(const __hip_bfloat16* __restrict__ A,
             const __hip_bfloat16* __restrict__ Bt,
             const float* __restrict__ bias,
             void* __restrict__ Cout, int M, int N, int K) {
  __shared__ __hip_bfloat16 lA[2][128 * 64];
  __shared__ __hip_bfloat16 lB[2][64 * 64];
  const int tid = threadIdx.x;
  const int lane = tid & 63, wv = tid >> 6;
  const int l16 = lane & 15, lg = lane >> 4;
  const int wm = wv >> 1, wn = wv & 1;
  const int xcd = blockIdx.x & 7, idx = blockIdx.x >> 3;
  const int tileM = (xcd * 4 + (idx >> 4)) * 128, tileN = (idx & 15) * 64;
  const int KB = K * 2;

  f32x4 acc[4][2] = {};
  const int o0 = wv * 1024 + lane * 16;

  auto GSTAGE = [&](int bi, int kt) {
#pragma unroll
    for (int j = 0; j < 4; ++j) {
      int o = o0 + j * 4096;
      int row = o >> 7, col = (o & 127) ^ ((row & 7) << 4);
      gload_lds16((const char*)A + (size_t)(tileM + row) * KB + kt * 2 + col,
                  (char*)lA[bi] + wv * 1024 + j * 4096);
    }
#pragma unroll
    for (int j = 0; j < 2; ++j) {
      int o = o0 + j * 4096;
      int row = o >> 7, col = (o & 127) ^ ((row & 7) << 4);
      gload_lds16((const char*)Bt + (size_t)(tileN + row) * KB + kt * 2 + col,
                  (char*)lB[bi] + wv * 1024 + j * 4096);
    }
  };

  GSTAGE(0, 0);
  drain_vmem();
  __syncthreads();
  int buf = 0;
  const int NT = K / 64;
  for (int t = 0; t < NT; ++t) {
    if (t + 1 < NT) GSTAGE(buf ^ 1, (t + 1) * 64);
    bf16x8 af[4][2], bfr[2][2];
#pragma unroll
    for (int mt = 0; mt < 4; ++mt) {
      const int row = wm * 64 + mt * 16 + l16;
      const int sw = (row & 7) << 4;
#pragma unroll
      for (int kk = 0; kk < 2; ++kk)
        af[mt][kk] = *(const bf16x8*)((const char*)lA[buf] + row * 128 + ((kk * 64 + lg * 16) ^ sw));
    }
#pragma unroll
    for (int nt = 0; nt < 2; ++nt) {
      const int row = wn * 32 + nt * 16 + l16;
      const int sw = (row & 7) << 4;
#pragma unroll
      for (int kk = 0; kk < 2; ++kk)
        bfr[nt][kk] = *(const bf16x8*)((const char*)lB[buf] + row * 128 + ((kk * 64 + lg * 16) ^ sw));
    }
#pragma unroll
    for (int kk = 0; kk < 2; ++kk)
#pragma unroll
      for (int mt = 0; mt < 4; ++mt)
#pragma unroll
        for (int nt = 0; nt < 2; ++nt)
          acc[mt][nt] = __builtin_amdgcn_mfma_f32_16x16x32_bf16(af[mt][kk], bfr[nt][kk], acc[mt][nt], 0, 0, 0);
    drain_vmem();
    __syncthreads();
    buf ^= 1;
  }

#pragma unroll
  for (int mt = 0; mt < 4; ++mt) {
#pragma unroll
    for (int nt = 0; nt < 2; ++nt) {
      int col = tileN + wn * 32 + nt * 16 + l16;
      float bcol = bias[col];
      int row0 = tileM + wm * 64 + mt * 16 + lg * 4;
      f32x4 a = acc[mt][nt];
#pragma unroll
      for (int r = 0; r < 4; ++r) {
        int row = row0 + r;
        float v = a[r] + bcol;
        if (MODE == 0) {
          ((__hip_bfloat16*)Cout)[(size_t)row * N + col] = __float2bfloat16(v);
        } else {
          ((float*)Cout)[(size_t)row * N + col] = v;
        }
      }
    }
  }
}

// ---------------- fused QKV projection: 256x128 tiles, XCD-clustered, 3-deep ----------------
// R11's race-proven 3-deep counted-vmcnt sync structure; tile enlarged to
// BM=256 x BN=128 (32 MFMA/barrier vs 16 — attacks the 2-phase stage+wait+
// barrier overhead that capped all 128^2 variants at ~490 TF). 6 loads/stage
// -> vmcnt(6). LDS 3 x 24KB = 72KB, 2 blocks/CU; acc 128 VGPR, ~196 total
// fits 2 waves/SIMD (launch_bounds(256,2)).
// Grid 640: xcd=bid&7, idx=bid>>3 (80/XCD): idx<16 -> Q tile, else KV tile.
__global__ __launch_bounds__(256, 2)
void gemm_qkv(const __hip_bfloat16* __restrict__ decB,
              const __hip_bfloat16* __restrict__ WqB,
              const float* __restrict__ bq,
              const __hip_bfloat16* __restrict__ encB,
              const __hip_bfloat16* __restrict__ WkvB,
              const float* __restrict__ bk,
              const float* __restrict__ bv,
              __hip_bfloat16* __restrict__ Qout,
              __hip_bfloat16* __restrict__ Kout,
              __hip_bfloat16* __restrict__ Vtout,
              const int* __restrict__ vmask) {
  const int K = 1024;
  __shared__ __hip_bfloat16 lA[3][256 * 32];   // 16KB each
  __shared__ __hip_bfloat16 lB[3][128 * 32];   //  8KB each
  const int tid = threadIdx.x;
  const int lane = tid & 63, wv = tid >> 6;
  const int l16 = lane & 15, lg = lane >> 4;
  const int wm = wv >> 1, wn = wv & 1;         // wm: 0..1 (128 rows), wn: 0..1 (64 cols)

  const int xcd = blockIdx.x & 7;
  const int idx = blockIdx.x >> 3;             // 0..79 within XCD
  const bool isQ = idx < 16;
  int tileM, tileN;
  const __hip_bfloat16 *A, *Bt;
  if (isQ) {
    int qt = xcd * 16 + idx;                   // 0..127
    tileM = (qt >> 3) * 256; tileN = (qt & 7) * 128;
    A = decB; Bt = WqB;
  } else {
    int kvt = xcd * 64 + (idx - 16);           // 0..511
    tileM = (kvt >> 4) * 256; tileN = (kvt & 15) * 128;
    A = encB; Bt = WkvB;
  }
  const int KB = K * 2;

  f32x4 acc[8][4] = {};
  const int o0 = tid * 16;

  auto GSTAGE = [&](int bi, int kt) {
#pragma unroll
    for (int j = 0; j < 4; ++j) {              // A: 256 rows x 64B = 16KB
      int o = o0 + j * 4096;
      int row = o >> 6, col = (o & 63) ^ ((row & 3) << 4);
      gload_lds16((const char*)A + (size_t)(tileM + row) * KB + kt * 2 + col,
                  (char*)lA[bi] + (tid & 192) * 16 + j * 4096);
    }
#pragma unroll
    for (int j = 0; j < 2; ++j) {              // B: 128 rows x 64B = 8KB
      int o = o0 + j * 4096;
      int row = o >> 6, col = (o & 63) ^ ((row & 3) << 4);
      gload_lds16((const char*)Bt + (size_t)(tileN + row) * KB + kt * 2 + col,
                  (char*)lB[bi] + (tid & 192) * 16 + j * 4096);
    }
  };

  GSTAGE(0, 0);
  GSTAGE(1, 32);
  const int NT = K / 32;                       // 32
  for (int t = 0; t < NT; ++t) {
    if (t < NT - 1) {
      asm volatile("s_waitcnt vmcnt(6)" ::: "memory");   // stage t landed; t+1 (6 loads) in flight
    } else {
      asm volatile("s_waitcnt vmcnt(0)" ::: "memory");
    }
    __builtin_amdgcn_sched_barrier(0);
    __syncthreads();
    if (t + 2 < NT) GSTAGE((t + 2) % 3, (t + 2) * 32);

    const int buf = t % 3;
    bf16x8 af[8], bfr[4];
#pragma unroll
    for (int mt = 0; mt < 8; ++mt) {
      const int row = wm * 128 + mt * 16 + l16;
      af[mt] = *(const bf16x8*)((const char*)lA[buf] + row * 64 + ((lg * 16) ^ ((row & 3) << 4)));
    }
#pragma unroll
    for (int nt = 0; nt < 4; ++nt) {
      const int row = wn * 64 + nt * 16 + l16;
      bfr[nt] = *(const bf16x8*)((const char*)lB[buf] + row * 64 + ((lg * 16) ^ ((row & 3) << 4)));
    }
#pragma unroll
    for (int mt = 0; mt < 8; ++mt)
#pragma unroll
      for (int nt = 0; nt < 4; ++nt)
        acc[mt][nt] = __builtin_amdgcn_mfma_f32_16x16x32_bf16(af[mt], bfr[nt], acc[mt][nt], 0, 0, 0);
  }

#pragma unroll
  for (int mt = 0; mt < 8; ++mt) {
#pragma unroll
    for (int nt = 0; nt < 4; ++nt) {
      int col = tileN + wn * 64 + nt * 16 + l16;
      int row0 = tileM + wm * 128 + mt * 16 + lg * 4;
      f32x4 a = acc[mt][nt];
      if (isQ) {
        float bc = bq[col];
#pragma unroll
        for (int r = 0; r < 4; ++r) {
          int row = row0 + r;
          Qout[(size_t)row * 1024 + col] = __float2bfloat16(a[r] + bc);
        }
      } else if (col < 1024) {
        float bc = bk[col];
#pragma unroll
        for (int r = 0; r < 4; ++r) {
          int row = row0 + r;
          Kout[(size_t)row * 1024 + col] = __float2bfloat16(a[r] + bc);
        }
      } else {
        int cv = col - 1024;
        float bc = bv[cv];
#pragma unroll
        for (int r = 0; r < 4; ++r) {
          int row = row0 + r;
          int b = row >> 11, kv = row & 2047;
          float v = a[r] + bc;
          if (!vmask[b * 2048 + kv]) v = 0.0f;
          Vtout[((size_t)(b * 1024 + cv)) * 2048 + kv] = __float2bfloat16(v);
        }
      }
    }
  }
}

// ---------------- flash attention, swapped-QK^T 32x32, KVBLK=128 (R14 proven) ----------------
__global__ __launch_bounds__(256, 2)
void attn_fwd(const __hip_bfloat16* __restrict__ Qg,
              const __hip_bfloat16* __restrict__ Kg,
              const __hip_bfloat16* __restrict__ Vt,
              const __hip_bfloat16* __restrict__ mkb,
              __hip_bfloat16* __restrict__ AO) {
  __shared__ __hip_bfloat16 lK[2][128 * 64];
  __shared__ __hip_bfloat16 lV[2][2][64 * 64];
  const int tid = threadIdx.x, lane = tid & 63, wv = tid >> 6;
  const int l32 = lane & 31, h = lane >> 5;

  const int blk = blockIdx.x;
  const int c8 = blk & 7, j = blk >> 3;
  const int g8 = c8 * 8 + (j & 7);   // (b,hd) group, clustered per XCD
  const int qi = j >> 3;
  const int hd = g8 & 15, b = g8 >> 4;
  const int qb = qi * 128;
  const int q0 = qb + wv * 32;

  const char* qbase = (const char*)Qg +
      ((size_t)(b * LQ_ + q0 + l32) * DM_ + hd * DH_ + h * 8) * 2;
  bf16x8 qf[4];
#pragma unroll
  for (int dk = 0; dk < 4; ++dk) qf[dk] = *(const bf16x8*)(qbase + dk * 32);

  f32x16 o_[2] = {};
  f32x16 l_acc = {};
  float m2 = -1e30f;                 // running max, log2 domain
  const float S2 = 0.18033688f;      // 0.125 * 1/ln2
  const __hip_bfloat16* mrow = mkb + b * LKV_;
  const char* Kbase = (const char*)Kg + ((size_t)(b * LKV_) * DM_ + hd * DH_) * 2;
  const char* Vbase = (const char*)Vt + ((size_t)((b * H_ + hd) * DH_)) * LKV_ * 2;

  const int ofs = wv * 1024 + lane * 16;

  auto STAGE = [&](int bi, int kv0) {
#pragma unroll
    for (int r = 0; r < 4; ++r) {
      int o = ofs + r * 4096;
      int row = o >> 7, col = (o & 127) ^ ((row & 7) << 4);
      gload_lds16(Kbase + (size_t)(kv0 + row) * 2048 + col,
                  (char*)lK[bi] + wv * 1024 + r * 4096);
    }
#pragma unroll
    for (int s = 0; s < 2; ++s)
#pragma unroll
      for (int r = 0; r < 2; ++r) {
        int o = ofs + r * 4096;
        int row = o >> 7, col = (o & 127) ^ ((row & 7) << 4);
        gload_lds16(Vbase + (size_t)row * 4096 + (kv0 + s * 64) * 2 + col,
                    (char*)lV[bi][s] + wv * 1024 + r * 4096);
      }
  };

  STAGE(0, 0);
  drain_vmem();
  __syncthreads();
  int buf = 0;

  for (int it = 0; it < LKV_ / 128; ++it) {
    const int kv0 = it * 128;
    if (it + 1 < LKV_ / 128) STAGE(buf ^ 1, kv0 + 128);

    // S^T = K Q^T : col = q = l32 ; row = kv = (g&3)+8*(g>>2)+4*h (+32t)
    f32x16 z[4];
#pragma unroll
    for (int t = 0; t < 4; ++t) {
      z[t] = {};
      const int row = t * 32 + l32;
      const int sw = (row & 7) << 4;
      const char* kp = (const char*)lK[buf] + row * 128;
      __builtin_amdgcn_s_setprio(1);
#pragma unroll
      for (int dk = 0; dk < 4; ++dk) {
        bf16x8 kf = *(const bf16x8*)(kp + ((dk * 32 + h * 16) ^ sw));
        z[t] = __builtin_amdgcn_mfma_f32_32x32x16_bf16(kf, qf[dk], z[t], 0, 0, 0);
      }
      __builtin_amdgcn_s_setprio(0);
    }

    // per-q max over 128 kv: balanced tree, lane-local + one cross-half reduce
    f32x16 zm;
#pragma unroll
    for (int g = 0; g < 16; ++g)
      zm[g] = fmaxf(fmaxf(z[0][g], z[1][g]), fmaxf(z[2][g], z[3][g]));
    float m0 = fmaxf(fmaxf(zm[0], zm[1]), fmaxf(zm[2], zm[3]));
    float m1 = fmaxf(fmaxf(zm[4], zm[5]), fmaxf(zm[6], zm[7]));
    float m4 = fmaxf(fmaxf(zm[8], zm[9]), fmaxf(zm[10], zm[11]));
    float m5 = fmaxf(fmaxf(zm[12], zm[13]), fmaxf(zm[14], zm[15]));
    float mx = fmaxf(fmaxf(m0, m1), fmaxf(m4, m5));
    mx = fmaxf(mx, __shfl_xor(mx, 32));
    float mx2 = mx * S2;

    // T13 defer-max (log2 domain, thr = 8/ln2)
    if (!__all(mx2 - m2 <= 11.5416f)) {
      float mn = fmaxf(m2, mx2);
      float alpha = EXP2(m2 - mn);
      m2 = mn;
#pragma unroll
      for (int g = 0; g < 16; ++g) {
        float a2 = __shfl(alpha, (g & 3) + 8 * (g >> 2) + 4 * h);
        o_[0][g] *= a2;
        o_[1][g] *= a2;
        l_acc[g] *= a2;
      }
    }

    // P = exp2(z*S2 - m2)
    const float negm2 = -m2;
    unsigned pk[4][4][2];
#pragma unroll
    for (int t = 0; t < 4; ++t)
#pragma unroll
      for (int s = 0; s < 4; ++s) {
        float p0 = EXP2(fmaf(z[t][s * 4 + 0], S2, negm2));
        float p1 = EXP2(fmaf(z[t][s * 4 + 1], S2, negm2));
        float p2 = EXP2(fmaf(z[t][s * 4 + 2], S2, negm2));
        float p3 = EXP2(fmaf(z[t][s * 4 + 3], S2, negm2));
        pk[t][s][0] = pack2(p0, p1);
        pk[t][s][1] = pack2(p2, p3);
      }

    // O += P V ; l_acc += P·mask   (8 chunks of 16 kv)
#pragma unroll
    for (int c = 0; c < 8; ++c) {
      const int t = c >> 1, cc = c & 1;
      const int s = c >> 2, cl = c & 3;
      unsigned w0 = pk[t][2 * cc + 0][0], w1 = pk[t][2 * cc + 0][1];
      unsigned w2 = pk[t][2 * cc + 1][0], w3 = pk[t][2 * cc + 1][1];
      xswap(w0, w2);
      xswap(w1, w3);
      union { unsigned w[4]; bf16x8 v; } au;
      au.w[0] = w0; au.w[1] = w1; au.w[2] = w2; au.w[3] = w3;
      bf16x8 mb8 = *(const bf16x8*)(mrow + kv0 + c * 16 + h * 8);
      __builtin_amdgcn_s_setprio(1);
#pragma unroll
      for (int dt = 0; dt < 2; ++dt) {
        const int row = dt * 32 + l32;
        const int sw = (row & 7) << 4;
        bf16x8 vf = *(const bf16x8*)((const char*)lV[buf][s] + row * 128 + ((cl * 32 + h * 16) ^ sw));
        o_[dt] = __builtin_amdgcn_mfma_f32_32x32x16_bf16(au.v, vf, o_[dt], 0, 0, 0);
      }
      l_acc = __builtin_amdgcn_mfma_f32_32x32x16_bf16(au.v, mb8, l_acc, 0, 0, 0);
      __builtin_amdgcn_s_setprio(0);
    }
    drain_vmem();
    __syncthreads();
    buf ^= 1;
  }

  // l_acc[g] = sum_kv P[q(g,h)][kv]*mask[kv] (identical across cols)
#pragma unroll
  for (int dt = 0; dt < 2; ++dt)
#pragma unroll
    for (int g = 0; g < 16; ++g) {
      int q = (g & 3) + 8 * (g >> 2) + 4 * h;
      AO[(size_t)(b * LQ_ + qb + wv * 32 + q) * DM_ + hd * DH_ + dt * 32 + l32] =
          __float2bfloat16(o_[dt][g] / l_acc[g]);
    }
}

// ---------------- launch ----------------
extern "C" void kernel_launch(void* const* d_in, const int* in_sizes, int n_in,
                              void* d_out, int out_size, void* d_ws, size_t ws_size,
                              hipStream_t stream) {
  const float* dec = (const float*)d_in[0];
  const float* enc = (const float*)d_in[1];
  const int*   msk = (const int*)d_in[2];
  const float* Wq = (const float*)d_in[3];
  const float* bq = (const float*)d_in[4];
  const float* Wk = (const float*)d_in[5];
  const float* bk = (const float*)d_in[6];
  const float* Wv = (const float*)d_in[7];
  const float* bv = (const float*)d_in[8];
  const float* Wo = (const float*)d_in[9];
  const float* bo = (const float*)d_in[10];

  char* ws = (char*)d_ws;
  __hip_bfloat16* decB = (__hip_bfloat16*)(ws);
  __hip_bfloat16* encB = (__hip_bfloat16*)(ws + 8388608);
  __hip_bfloat16* WqB  = (__hip_bfloat16*)(ws + 25165824);
  __hip_bfloat16* WkvB = (__hip_bfloat16*)(ws + 27262976);  // [2048][1024] = Wk ; Wv
  __hip_bfloat16* WoB  = (__hip_bfloat16*)(ws + 31457280);
  __hip_bfloat16* Qb   = (__hip_bfloat16*)(ws + 33554432);
  __hip_bfloat16* Kb   = (__hip_bfloat16*)(ws + 41943040);
  __hip_bfloat16* Vtb  = (__hip_bfloat16*)(ws + 58720256);  // [B,H,Dh,Lkv]
  __hip_bfloat16* AO   = (__hip_bfloat16*)(ws + 75497472);
  __hip_bfloat16* mk2  = (__hip_bfloat16*)(ws + 83886080);  // bf16 0/1 mask

  CastArgs ca;
  ca.src[0] = dec; ca.dst[0] = decB;             ca.n[0] = 4096 * 1024;
  ca.src[1] = enc; ca.dst[1] = encB;             ca.n[1] = 8192 * 1024;
  ca.src[2] = Wq;  ca.dst[2] = WqB;              ca.n[2] = 1024 * 1024;
  ca.src[3] = Wk;  ca.dst[3] = WkvB;             ca.n[3] = 1024 * 1024;
  ca.src[4] = Wv;  ca.dst[4] = WkvB + 1048576;   ca.n[4] = 1024 * 1024;
  ca.src[5] = Wo;  ca.dst[5] = WoB;              ca.n[5] = 1024 * 1024;
  cast_multi<<<dim3(4096, 6), dim3(256), 0, stream>>>(ca);
  mask_mul<<<dim3(32), dim3(256), 0, stream>>>(msk, mk2, B_ * LKV_);

  gemm_qkv<<<dim3(640), dim3(256), 0, stream>>>(decB, WqB, bq, encB, WkvB, bk, bv,
                                                Qb, Kb, Vtb, msk);

  attn_fwd<<<dim3(512), dim3(256), 0, stream>>>(Qb, Kb, Vtb, mk2, AO);

  gemm_bt<2><<<dim3(512), dim3(256), 0, stream>>>(AO, WoB, bo, d_out, 4096, 1024, 1024);
}

// Round 18
// 176.772 us; speedup vs baseline: 1.1209x; 1.1209x over previous
//
#include <hip/hip_runtime.h>
#include <hip/hip_bf16.h>
#include <stdint.h>
#include <math.h>

#define B_   4
#define H_   16
#define LQ_  1024
#define LKV_ 2048
#define DM_  1024
#define DH_  64

typedef __attribute__((ext_vector_type(8))) __bf16 bf16x8;
typedef __attribute__((ext_vector_type(4))) float  f32x4;
typedef __attribute__((ext_vector_type(16))) float f32x16;
typedef __attribute__((ext_vector_type(8))) short  short8;
typedef __attribute__((ext_vector_type(2))) unsigned uint2v;

__device__ __forceinline__ void gload_lds16(const void* g, void* l) {
  __builtin_amdgcn_global_load_lds(
      (const __attribute__((address_space(1))) void*)g,
      (__attribute__((address_space(3))) void*)l, 16, 0, 0);
}

// Explicit LDS-DMA drain before publishing barrier (race-proven in R3).
__device__ __forceinline__ void drain_vmem() {
  asm volatile("s_waitcnt vmcnt(0)" ::: "memory");
  __builtin_amdgcn_sched_barrier(0);
}

// Raw v_exp_f32 (exp2): OCML exp2f has denorm fixup (R4 regression).
#if __has_builtin(__builtin_amdgcn_exp2f)
__device__ __forceinline__ float EXP2(float x) { return __builtin_amdgcn_exp2f(x); }
#else
__device__ __forceinline__ float EXP2(float x) {
  float r; asm("v_exp_f32 %0, %1" : "=v"(r) : "v"(x)); return r;
}
#endif

// a' = [a.lo32, b.lo32], b' = [a.hi32, b.hi32]
#if __has_builtin(__builtin_amdgcn_permlane32_swap)
__device__ __forceinline__ void xswap(unsigned& a, unsigned& b) {
  uint2v r = __builtin_amdgcn_permlane32_swap(a, b, false, false);
  a = r[0]; b = r[1];
}
#else
__device__ __forceinline__ void xswap(unsigned& a, unsigned& b) {
  unsigned xa = (unsigned)__shfl_xor((int)a, 32);
  unsigned xb = (unsigned)__shfl_xor((int)b, 32);
  bool hi = (threadIdx.x & 32) != 0;
  unsigned na = hi ? xb : a;
  unsigned nb = hi ? b : xa;
  a = na; b = nb;
}
#endif

__device__ __forceinline__ unsigned pack2(float a, float b) {
  unsigned lo = (unsigned)__bfloat16_as_ushort(__float2bfloat16(a));
  unsigned hi = (unsigned)__bfloat16_as_ushort(__float2bfloat16(b));
  return lo | (hi << 16);
}

// ---------------- fused fp32 -> bf16 cast (+ mask row, seg 6) ----------------
struct CastArgs {
  const float* src[6];
  __hip_bfloat16* dst[6];
  int n[6];
  const int* msk;
  __hip_bfloat16* mdst;
  int mn;
};

__global__ void cast_multi(CastArgs a) {
  int seg = blockIdx.y;
  int i = (blockIdx.x * blockDim.x + threadIdx.x) * 8;
  if (seg == 6) {
    if (i >= a.mn) return;
    const int* s = a.msk + i;
    union { short8 v; __hip_bfloat16 h[8]; } u;
#pragma unroll
    for (int j = 0; j < 8; ++j) u.h[j] = __float2bfloat16(s[j] ? 1.0f : 0.0f);
    *(short8*)(a.mdst + i) = u.v;
    return;
  }
  int n = a.n[seg];
  if (i >= n) return;
  const float* s = a.src[seg] + i;
  float4 x = *(const float4*)s;
  float4 y = *(const float4*)(s + 4);
  union { short8 v; __hip_bfloat16 h[8]; } u;
  u.h[0] = __float2bfloat16(x.x); u.h[1] = __float2bfloat16(x.y);
  u.h[2] = __float2bfloat16(x.z); u.h[3] = __float2bfloat16(x.w);
  u.h[4] = __float2bfloat16(y.x); u.h[5] = __float2bfloat16(y.y);
  u.h[6] = __float2bfloat16(y.z); u.h[7] = __float2bfloat16(y.w);
  *(short8*)(a.dst[seg] + i) = u.v;
}

// ---------------- GEMM 128x64 (O projection), XCD-bijective 1D grid (R16 proven) ----------------
template<int MODE>
__global__ __launch_bounds__(256, 3)
void gemm_bt(const __hip_bfloat16* __restrict__ A,
             const __hip_bfloat16* __restrict__ Bt,
             const float* __restrict__ bias,
             void* __restrict__ Cout, int M, int N, int K) {
  __shared__ __hip_bfloat16 lA[2][128 * 64];
  __shared__ __hip_bfloat16 lB[2][64 * 64];
  const int tid = threadIdx.x;
  const int lane = tid & 63, wv = tid >> 6;
  const int l16 = lane & 15, lg = lane >> 4;
  const int wm = wv >> 1, wn = wv & 1;
  const int xcd = blockIdx.x & 7, idx = blockIdx.x >> 3;
  const int tileM = (xcd * 4 + (idx >> 4)) * 128, tileN = (idx & 15) * 64;
  const int KB = K * 2;

  f32x4 acc[4][2] = {};
  const int o0 = wv * 1024 + lane * 16;

  auto GSTAGE = [&](int bi, int kt) {
#pragma unroll
    for (int j = 0; j < 4; ++j) {
      int o = o0 + j * 4096;
      int row = o >> 7, col = (o & 127) ^ ((row & 7) << 4);
      gload_lds16((const char*)A + (size_t)(tileM + row) * KB + kt * 2 + col,
                  (char*)lA[bi] + wv * 1024 + j * 4096);
    }
#pragma unroll
    for (int j = 0; j < 2; ++j) {
      int o = o0 + j * 4096;
      int row = o >> 7, col = (o & 127) ^ ((row & 7) << 4);
      gload_lds16((const char*)Bt + (size_t)(tileN + row) * KB + kt * 2 + col,
                  (char*)lB[bi] + wv * 1024 + j * 4096);
    }
  };

  GSTAGE(0, 0);
  drain_vmem();
  __syncthreads();
  int buf = 0;
  const int NT = K / 64;
  for (int t = 0; t < NT; ++t) {
    if (t + 1 < NT) GSTAGE(buf ^ 1, (t + 1) * 64);
    bf16x8 af[4][2], bfr[2][2];
#pragma unroll
    for (int mt = 0; mt < 4; ++mt) {
      const int row = wm * 64 + mt * 16 + l16;
      const int sw = (row & 7) << 4;
#pragma unroll
      for (int kk = 0; kk < 2; ++kk)
        af[mt][kk] = *(const bf16x8*)((const char*)lA[buf] + row * 128 + ((kk * 64 + lg * 16) ^ sw));
    }
#pragma unroll
    for (int nt = 0; nt < 2; ++nt) {
      const int row = wn * 32 + nt * 16 + l16;
      const int sw = (row & 7) << 4;
#pragma unroll
      for (int kk = 0; kk < 2; ++kk)
        bfr[nt][kk] = *(const bf16x8*)((const char*)lB[buf] + row * 128 + ((kk * 64 + lg * 16) ^ sw));
    }
#pragma unroll
    for (int kk = 0; kk < 2; ++kk)
#pragma unroll
      for (int mt = 0; mt < 4; ++mt)
#pragma unroll
        for (int nt = 0; nt < 2; ++nt)
          acc[mt][nt] = __builtin_amdgcn_mfma_f32_16x16x32_bf16(af[mt][kk], bfr[nt][kk], acc[mt][nt], 0, 0, 0);
    drain_vmem();
    __syncthreads();
    buf ^= 1;
  }

#pragma unroll
  for (int mt = 0; mt < 4; ++mt) {
#pragma unroll
    for (int nt = 0; nt < 2; ++nt) {
      int col = tileN + wn * 32 + nt * 16 + l16;
      float bcol = bias[col];
      int row0 = tileM + wm * 64 + mt * 16 + lg * 4;
      f32x4 a = acc[mt][nt];
#pragma unroll
      for (int r = 0; r < 4; ++r) {
        int row = row0 + r;
        float v = a[r] + bcol;
        if (MODE == 0) {
          ((__hip_bfloat16*)Cout)[(size_t)row * N + col] = __float2bfloat16(v);
        } else {
          ((float*)Cout)[(size_t)row * N + col] = v;
        }
      }
    }
  }
}

// ---------------- fused QKV projection: XCD-clustered + 3-deep pipeline (R11/R16 proven) ----------------
__global__ __launch_bounds__(256, 3)
void gemm_qkv(const __hip_bfloat16* __restrict__ decB,
              const __hip_bfloat16* __restrict__ WqB,
              const float* __restrict__ bq,
              const __hip_bfloat16* __restrict__ encB,
              const __hip_bfloat16* __restrict__ WkvB,
              const float* __restrict__ bk,
              const float* __restrict__ bv,
              __hip_bfloat16* __restrict__ Qout,
              __hip_bfloat16* __restrict__ Kout,
              __hip_bfloat16* __restrict__ Vtout,
              const int* __restrict__ vmask) {
  const int K = 1024;
  __shared__ __hip_bfloat16 lA[3][128 * 32];
  __shared__ __hip_bfloat16 lB[3][128 * 32];
  const int tid = threadIdx.x;
  const int lane = tid & 63, wv = tid >> 6;
  const int l16 = lane & 15, lg = lane >> 4;
  const int wm = wv >> 1, wn = wv & 1;

  const int xcd = blockIdx.x & 7;
  const int idx = blockIdx.x >> 3;       // 0..159 within XCD
  const bool isQ = idx < 32;
  int tileM, tileN;
  const __hip_bfloat16 *A, *Bt;
  if (isQ) {
    int qt = xcd * 32 + idx;             // 0..255
    tileM = (qt >> 3) * 128; tileN = (qt & 7) * 128;
    A = decB; Bt = WqB;
  } else {
    int kvt = xcd * 128 + (idx - 32);    // 0..1023
    tileM = (kvt >> 4) * 128; tileN = (kvt & 15) * 128;
    A = encB; Bt = WkvB;
  }
  const int KB = K * 2;

  f32x4 acc[4][4] = {};
  const int o0 = tid * 16;

  auto GSTAGE = [&](int bi, int kt) {
#pragma unroll
    for (int j = 0; j < 2; ++j) {
      int o = o0 + j * 4096;
      int row = o >> 6, col = (o & 63) ^ ((row & 3) << 4);
      gload_lds16((const char*)A + (size_t)(tileM + row) * KB + kt * 2 + col,
                  (char*)lA[bi] + (tid & 192) * 16 + j * 4096);
    }
#pragma unroll
    for (int j = 0; j < 2; ++j) {
      int o = o0 + j * 4096;
      int row = o >> 6, col = (o & 63) ^ ((row & 3) << 4);
      gload_lds16((const char*)Bt + (size_t)(tileN + row) * KB + kt * 2 + col,
                  (char*)lB[bi] + (tid & 192) * 16 + j * 4096);
    }
  };

  GSTAGE(0, 0);
  GSTAGE(1, 32);
  const int NT = K / 32;                 // 32
  for (int t = 0; t < NT; ++t) {
    if (t < NT - 1) {
      asm volatile("s_waitcnt vmcnt(4)" ::: "memory");
    } else {
      asm volatile("s_waitcnt vmcnt(0)" ::: "memory");
    }
    __builtin_amdgcn_sched_barrier(0);
    __syncthreads();
    if (t + 2 < NT) GSTAGE((t + 2) % 3, (t + 2) * 32);

    const int buf = t % 3;
    bf16x8 af[4], bfr[4];
#pragma unroll
    for (int mt = 0; mt < 4; ++mt) {
      const int row = wm * 64 + mt * 16 + l16;
      af[mt] = *(const bf16x8*)((const char*)lA[buf] + row * 64 + ((lg * 16) ^ ((row & 3) << 4)));
    }
#pragma unroll
    for (int nt = 0; nt < 4; ++nt) {
      const int row = wn * 64 + nt * 16 + l16;
      bfr[nt] = *(const bf16x8*)((const char*)lB[buf] + row * 64 + ((lg * 16) ^ ((row & 3) << 4)));
    }
#pragma unroll
    for (int mt = 0; mt < 4; ++mt)
#pragma unroll
      for (int nt = 0; nt < 4; ++nt)
        acc[mt][nt] = __builtin_amdgcn_mfma_f32_16x16x32_bf16(af[mt], bfr[nt], acc[mt][nt], 0, 0, 0);
  }

#pragma unroll
  for (int mt = 0; mt < 4; ++mt) {
#pragma unroll
    for (int nt = 0; nt < 4; ++nt) {
      int col = tileN + wn * 64 + nt * 16 + l16;
      int row0 = tileM + wm * 64 + mt * 16 + lg * 4;
      f32x4 a = acc[mt][nt];
      if (isQ) {
        float bc = bq[col];
#pragma unroll
        for (int r = 0; r < 4; ++r) {
          int row = row0 + r;
          Qout[(size_t)row * 1024 + col] = __float2bfloat16(a[r] + bc);
        }
      } else if (col < 1024) {
        float bc = bk[col];
#pragma unroll
        for (int r = 0; r < 4; ++r) {
          int row = row0 + r;
          Kout[(size_t)row * 1024 + col] = __float2bfloat16(a[r] + bc);
        }
      } else {
        int cv = col - 1024;
        float bc = bv[cv];
#pragma unroll
        for (int r = 0; r < 4; ++r) {
          int row = row0 + r;
          int b = row >> 11, kv = row & 2047;
          float v = a[r] + bc;
          if (!vmask[b * 2048 + kv]) v = 0.0f;
          Vtout[((size_t)(b * 1024 + cv)) * 2048 + kv] = __float2bfloat16(v);
        }
      }
    }
  }
}

// ---------------- flash attention, swapped-QK^T 32x32, KVBLK=128 (R14 proven) ----------------
__global__ __launch_bounds__(256, 2)
void attn_fwd(const __hip_bfloat16* __restrict__ Qg,
              const __hip_bfloat16* __restrict__ Kg,
              const __hip_bfloat16* __restrict__ Vt,
              const __hip_bfloat16* __restrict__ mkb,
              __hip_bfloat16* __restrict__ AO) {
  __shared__ __hip_bfloat16 lK[2][128 * 64];
  __shared__ __hip_bfloat16 lV[2][2][64 * 64];
  const int tid = threadIdx.x, lane = tid & 63, wv = tid >> 6;
  const int l32 = lane & 31, h = lane >> 5;

  const int blk = blockIdx.x;
  const int c8 = blk & 7, j = blk >> 3;
  const int g8 = c8 * 8 + (j & 7);   // (b,hd) group, clustered per XCD
  const int qi = j >> 3;
  const int hd = g8 & 15, b = g8 >> 4;
  const int qb = qi * 128;
  const int q0 = qb + wv * 32;

  const char* qbase = (const char*)Qg +
      ((size_t)(b * LQ_ + q0 + l32) * DM_ + hd * DH_ + h * 8) * 2;
  bf16x8 qf[4];
#pragma unroll
  for (int dk = 0; dk < 4; ++dk) qf[dk] = *(const bf16x8*)(qbase + dk * 32);

  f32x16 o_[2] = {};
  f32x16 l_acc = {};
  float m2 = -1e30f;                 // running max, log2 domain
  const float S2 = 0.18033688f;      // 0.125 * 1/ln2
  const __hip_bfloat16* mrow = mkb + b * LKV_;
  const char* Kbase = (const char*)Kg + ((size_t)(b * LKV_) * DM_ + hd * DH_) * 2;
  const char* Vbase = (const char*)Vt + ((size_t)((b * H_ + hd) * DH_)) * LKV_ * 2;

  const int ofs = wv * 1024 + lane * 16;

  auto STAGE = [&](int bi, int kv0) {
#pragma unroll
    for (int r = 0; r < 4; ++r) {
      int o = ofs + r * 4096;
      int row = o >> 7, col = (o & 127) ^ ((row & 7) << 4);
      gload_lds16(Kbase + (size_t)(kv0 + row) * 2048 + col,
                  (char*)lK[bi] + wv * 1024 + r * 4096);
    }
#pragma unroll
    for (int s = 0; s < 2; ++s)
#pragma unroll
      for (int r = 0; r < 2; ++r) {
        int o = ofs + r * 4096;
        int row = o >> 7, col = (o & 127) ^ ((row & 7) << 4);
        gload_lds16(Vbase + (size_t)row * 4096 + (kv0 + s * 64) * 2 + col,
                    (char*)lV[bi][s] + wv * 1024 + r * 4096);
      }
  };

  STAGE(0, 0);
  drain_vmem();
  __syncthreads();
  int buf = 0;

  for (int it = 0; it < LKV_ / 128; ++it) {
    const int kv0 = it * 128;
    if (it + 1 < LKV_ / 128) STAGE(buf ^ 1, kv0 + 128);

    // S^T = K Q^T : col = q = l32 ; row = kv = (g&3)+8*(g>>2)+4*h (+32t)
    f32x16 z[4];
#pragma unroll
    for (int t = 0; t < 4; ++t) {
      z[t] = {};
      const int row = t * 32 + l32;
      const int sw = (row & 7) << 4;
      const char* kp = (const char*)lK[buf] + row * 128;
      __builtin_amdgcn_s_setprio(1);
#pragma unroll
      for (int dk = 0; dk < 4; ++dk) {
        bf16x8 kf = *(const bf16x8*)(kp + ((dk * 32 + h * 16) ^ sw));
        z[t] = __builtin_amdgcn_mfma_f32_32x32x16_bf16(kf, qf[dk], z[t], 0, 0, 0);
      }
      __builtin_amdgcn_s_setprio(0);
    }

    // per-q max over 128 kv: balanced tree, lane-local + one cross-half reduce
    f32x16 zm;
#pragma unroll
    for (int g = 0; g < 16; ++g)
      zm[g] = fmaxf(fmaxf(z[0][g], z[1][g]), fmaxf(z[2][g], z[3][g]));
    float m0 = fmaxf(fmaxf(zm[0], zm[1]), fmaxf(zm[2], zm[3]));
    float m1 = fmaxf(fmaxf(zm[4], zm[5]), fmaxf(zm[6], zm[7]));
    float m4 = fmaxf(fmaxf(zm[8], zm[9]), fmaxf(zm[10], zm[11]));
    float m5 = fmaxf(fmaxf(zm[12], zm[13]), fmaxf(zm[14], zm[15]));
    float mx = fmaxf(fmaxf(m0, m1), fmaxf(m4, m5));
    mx = fmaxf(mx, __shfl_xor(mx, 32));
    float mx2 = mx * S2;

    // T13 defer-max (log2 domain, thr = 8/ln2)
    if (!__all(mx2 - m2 <= 11.5416f)) {
      float mn = fmaxf(m2, mx2);
      float alpha = EXP2(m2 - mn);
      m2 = mn;
#pragma unroll
      for (int g = 0; g < 16; ++g) {
        float a2 = __shfl(alpha, (g & 3) + 8 * (g >> 2) + 4 * h);
        o_[0][g] *= a2;
        o_[1][g] *= a2;
        l_acc[g] *= a2;
      }
    }

    // P = exp2(z*S2 - m2)
    const float negm2 = -m2;
    unsigned pk[4][4][2];
#pragma unroll
    for (int t = 0; t < 4; ++t)
#pragma unroll
      for (int s = 0; s < 4; ++s) {
        float p0 = EXP2(fmaf(z[t][s * 4 + 0], S2, negm2));
        float p1 = EXP2(fmaf(z[t][s * 4 + 1], S2, negm2));
        float p2 = EXP2(fmaf(z[t][s * 4 + 2], S2, negm2));
        float p3 = EXP2(fmaf(z[t][s * 4 + 3], S2, negm2));
        pk[t][s][0] = pack2(p0, p1);
        pk[t][s][1] = pack2(p2, p3);
      }

    // O += P V ; l_acc += P·mask   (8 chunks of 16 kv)
#pragma unroll
    for (int c = 0; c < 8; ++c) {
      const int t = c >> 1, cc = c & 1;
      const int s = c >> 2, cl = c & 3;
      unsigned w0 = pk[t][2 * cc + 0][0], w1 = pk[t][2 * cc + 0][1];
      unsigned w2 = pk[t][2 * cc + 1][0], w3 = pk[t][2 * cc + 1][1];
      xswap(w0, w2);
      xswap(w1, w3);
      union { unsigned w[4]; bf16x8 v; } au;
      au.w[0] = w0; au.w[1] = w1; au.w[2] = w2; au.w[3] = w3;
      bf16x8 mb8 = *(const bf16x8*)(mrow + kv0 + c * 16 + h * 8);
      __builtin_amdgcn_s_setprio(1);
#pragma unroll
      for (int dt = 0; dt < 2; ++dt) {
        const int row = dt * 32 + l32;
        const int sw = (row & 7) << 4;
        bf16x8 vf = *(const bf16x8*)((const char*)lV[buf][s] + row * 128 + ((cl * 32 + h * 16) ^ sw));
        o_[dt] = __builtin_amdgcn_mfma_f32_32x32x16_bf16(au.v, vf, o_[dt], 0, 0, 0);
      }
      l_acc = __builtin_amdgcn_mfma_f32_32x32x16_bf16(au.v, mb8, l_acc, 0, 0, 0);
      __builtin_amdgcn_s_setprio(0);
    }
    drain_vmem();
    __syncthreads();
    buf ^= 1;
  }

  // l_acc[g] = sum_kv P[q(g,h)][kv]*mask[kv] (identical across cols)
#pragma unroll
  for (int dt = 0; dt < 2; ++dt)
#pragma unroll
    for (int g = 0; g < 16; ++g) {
      int q = (g & 3) + 8 * (g >> 2) + 4 * h;
      AO[(size_t)(b * LQ_ + qb + wv * 32 + q) * DM_ + hd * DH_ + dt * 32 + l32] =
          __float2bfloat16(o_[dt][g] / l_acc[g]);
    }
}

// ---------------- launch ----------------
extern "C" void kernel_launch(void* const* d_in, const int* in_sizes, int n_in,
                              void* d_out, int out_size, void* d_ws, size_t ws_size,
                              hipStream_t stream) {
  const float* dec = (const float*)d_in[0];
  const float* enc = (const float*)d_in[1];
  const int*   msk = (const int*)d_in[2];
  const float* Wq = (const float*)d_in[3];
  const float* bq = (const float*)d_in[4];
  const float* Wk = (const float*)d_in[5];
  const float* bk = (const float*)d_in[6];
  const float* Wv = (const float*)d_in[7];
  const float* bv = (const float*)d_in[8];
  const float* Wo = (const float*)d_in[9];
  const float* bo = (const float*)d_in[10];

  char* ws = (char*)d_ws;
  __hip_bfloat16* decB = (__hip_bfloat16*)(ws);
  __hip_bfloat16* encB = (__hip_bfloat16*)(ws + 8388608);
  __hip_bfloat16* WqB  = (__hip_bfloat16*)(ws + 25165824);
  __hip_bfloat16* WkvB = (__hip_bfloat16*)(ws + 27262976);  // [2048][1024] = Wk ; Wv
  __hip_bfloat16* WoB  = (__hip_bfloat16*)(ws + 31457280);
  __hip_bfloat16* Qb   = (__hip_bfloat16*)(ws + 33554432);
  __hip_bfloat16* Kb   = (__hip_bfloat16*)(ws + 41943040);
  __hip_bfloat16* Vtb  = (__hip_bfloat16*)(ws + 58720256);  // [B,H,Dh,Lkv]
  __hip_bfloat16* AO   = (__hip_bfloat16*)(ws + 75497472);
  __hip_bfloat16* mk2  = (__hip_bfloat16*)(ws + 83886080);  // bf16 0/1 mask

  CastArgs ca;
  ca.src[0] = dec; ca.dst[0] = decB;             ca.n[0] = 4096 * 1024;
  ca.src[1] = enc; ca.dst[1] = encB;             ca.n[1] = 8192 * 1024;
  ca.src[2] = Wq;  ca.dst[2] = WqB;              ca.n[2] = 1024 * 1024;
  ca.src[3] = Wk;  ca.dst[3] = WkvB;             ca.n[3] = 1024 * 1024;
  ca.src[4] = Wv;  ca.dst[4] = WkvB + 1048576;   ca.n[4] = 1024 * 1024;
  ca.src[5] = Wo;  ca.dst[5] = WoB;              ca.n[5] = 1024 * 1024;
  ca.msk = msk; ca.mdst = mk2; ca.mn = B_ * LKV_;
  cast_multi<<<dim3(4096, 7), dim3(256), 0, stream>>>(ca);

  gemm_qkv<<<dim3(1280), dim3(256), 0, stream>>>(decB, WqB, bq, encB, WkvB, bk, bv,
                                                 Qb, Kb, Vtb, msk);

  attn_fwd<<<dim3(512), dim3(256), 0, stream>>>(Qb, Kb, Vtb, mk2, AO);

  gemm_bt<2><<<dim3(512), dim3(256), 0, stream>>>(AO, WoB, bo, d_out, 4096, 1024, 1024);
}

// Round 19
// 153.965 us; speedup vs baseline: 1.2869x; 1.1481x over previous
//
#include <hip/hip_runtime.h>
#include <hip/hip_bf16.h>
#include <stdint.h>
#include <math.h>

#define B_   4
#define H_   16
#define LQ_  1024
#define LKV_ 2048
#define DM_  1024
#define DH_  64

typedef __attribute__((ext_vector_type(8))) __bf16 bf16x8;
typedef __attribute__((ext_vector_type(4))) float  f32x4;
typedef __attribute__((ext_vector_type(16))) float f32x16;
typedef __attribute__((ext_vector_type(8))) short  short8;
typedef __attribute__((ext_vector_type(2))) unsigned uint2v;

__device__ __forceinline__ void gload_lds16(const void* g, void* l) {
  __builtin_amdgcn_global_load_lds(
      (const __attribute__((address_space(1))) void*)g,
      (__attribute__((address_space(3))) void*)l, 16, 0, 0);
}

// Explicit LDS-DMA drain before publishing barrier (race-proven in R3).
__device__ __forceinline__ void drain_vmem() {
  asm volatile("s_waitcnt vmcnt(0)" ::: "memory");
  __builtin_amdgcn_sched_barrier(0);
}

// Raw v_exp_f32 (exp2): OCML exp2f has denorm fixup (R4 regression).
#if __has_builtin(__builtin_amdgcn_exp2f)
__device__ __forceinline__ float EXP2(float x) { return __builtin_amdgcn_exp2f(x); }
#else
__device__ __forceinline__ float EXP2(float x) {
  float r; asm("v_exp_f32 %0, %1" : "=v"(r) : "v"(x)); return r;
}
#endif

// a' = [a.lo32, b.lo32], b' = [a.hi32, b.hi32]
#if __has_builtin(__builtin_amdgcn_permlane32_swap)
__device__ __forceinline__ void xswap(unsigned& a, unsigned& b) {
  uint2v r = __builtin_amdgcn_permlane32_swap(a, b, false, false);
  a = r[0]; b = r[1];
}
#else
__device__ __forceinline__ void xswap(unsigned& a, unsigned& b) {
  unsigned xa = (unsigned)__shfl_xor((int)a, 32);
  unsigned xb = (unsigned)__shfl_xor((int)b, 32);
  bool hi = (threadIdx.x & 32) != 0;
  unsigned na = hi ? xb : a;
  unsigned nb = hi ? b : xa;
  a = na; b = nb;
}
#endif

__device__ __forceinline__ unsigned pack2(float a, float b) {
  unsigned lo = (unsigned)__bfloat16_as_ushort(__float2bfloat16(a));
  unsigned hi = (unsigned)__bfloat16_as_ushort(__float2bfloat16(b));
  return lo | (hi << 16);
}

// ---------------- fused fp32 -> bf16 cast (+ mask row, seg 6) ----------------
struct CastArgs {
  const float* src[6];
  __hip_bfloat16* dst[6];
  int n[6];
  const int* msk;
  __hip_bfloat16* mdst;
  int mn;
};

__global__ void cast_multi(CastArgs a) {
  int seg = blockIdx.y;
  int i = (blockIdx.x * blockDim.x + threadIdx.x) * 8;
  if (seg == 6) {
    if (i >= a.mn) return;
    const int* s = a.msk + i;
    union { short8 v; __hip_bfloat16 h[8]; } u;
#pragma unroll
    for (int j = 0; j < 8; ++j) u.h[j] = __float2bfloat16(s[j] ? 1.0f : 0.0f);
    *(short8*)(a.mdst + i) = u.v;
    return;
  }
  int n = a.n[seg];
  if (i >= n) return;
  const float* s = a.src[seg] + i;
  float4 x = *(const float4*)s;
  float4 y = *(const float4*)(s + 4);
  union { short8 v; __hip_bfloat16 h[8]; } u;
  u.h[0] = __float2bfloat16(x.x); u.h[1] = __float2bfloat16(x.y);
  u.h[2] = __float2bfloat16(x.z); u.h[3] = __float2bfloat16(x.w);
  u.h[4] = __float2bfloat16(y.x); u.h[5] = __float2bfloat16(y.y);
  u.h[6] = __float2bfloat16(y.z); u.h[7] = __float2bfloat16(y.w);
  *(short8*)(a.dst[seg] + i) = u.v;
}

// ---------------- GEMM 128x64 (O projection), XCD-bijective 1D grid (R16 proven) ----------------
template<int MODE>
__global__ __launch_bounds__(256, 3)
void gemm_bt(const __hip_bfloat16* __restrict__ A,
             const __hip_bfloat16* __restrict__ Bt,
             const float* __restrict__ bias,
             void* __restrict__ Cout, int M, int N, int K) {
  __shared__ __hip_bfloat16 lA[2][128 * 64];
  __shared__ __hip_bfloat16 lB[2][64 * 64];
  const int tid = threadIdx.x;
  const int lane = tid & 63, wv = tid >> 6;
  const int l16 = lane & 15, lg = lane >> 4;
  const int wm = wv >> 1, wn = wv & 1;
  const int xcd = blockIdx.x & 7, idx = blockIdx.x >> 3;
  const int tileM = (xcd * 4 + (idx >> 4)) * 128, tileN = (idx & 15) * 64;
  const int KB = K * 2;

  f32x4 acc[4][2] = {};
  const int o0 = wv * 1024 + lane * 16;

  auto GSTAGE = [&](int bi, int kt) {
#pragma unroll
    for (int j = 0; j < 4; ++j) {
      int o = o0 + j * 4096;
      int row = o >> 7, col = (o & 127) ^ ((row & 7) << 4);
      gload_lds16((const char*)A + (size_t)(tileM + row) * KB + kt * 2 + col,
                  (char*)lA[bi] + wv * 1024 + j * 4096);
    }
#pragma unroll
    for (int j = 0; j < 2; ++j) {
      int o = o0 + j * 4096;
      int row = o >> 7, col = (o & 127) ^ ((row & 7) << 4);
      gload_lds16((const char*)Bt + (size_t)(tileN + row) * KB + kt * 2 + col,
                  (char*)lB[bi] + wv * 1024 + j * 4096);
    }
  };

  GSTAGE(0, 0);
  drain_vmem();
  __syncthreads();
  int buf = 0;
  const int NT = K / 64;
  for (int t = 0; t < NT; ++t) {
    if (t + 1 < NT) GSTAGE(buf ^ 1, (t + 1) * 64);
    bf16x8 af[4][2], bfr[2][2];
#pragma unroll
    for (int mt = 0; mt < 4; ++mt) {
      const int row = wm * 64 + mt * 16 + l16;
      const int sw = (row & 7) << 4;
#pragma unroll
      for (int kk = 0; kk < 2; ++kk)
        af[mt][kk] = *(const bf16x8*)((const char*)lA[buf] + row * 128 + ((kk * 64 + lg * 16) ^ sw));
    }
#pragma unroll
    for (int nt = 0; nt < 2; ++nt) {
      const int row = wn * 32 + nt * 16 + l16;
      const int sw = (row & 7) << 4;
#pragma unroll
      for (int kk = 0; kk < 2; ++kk)
        bfr[nt][kk] = *(const bf16x8*)((const char*)lB[buf] + row * 128 + ((kk * 64 + lg * 16) ^ sw));
    }
#pragma unroll
    for (int kk = 0; kk < 2; ++kk)
#pragma unroll
      for (int mt = 0; mt < 4; ++mt)
#pragma unroll
        for (int nt = 0; nt < 2; ++nt)
          acc[mt][nt] = __builtin_amdgcn_mfma_f32_16x16x32_bf16(af[mt][kk], bfr[nt][kk], acc[mt][nt], 0, 0, 0);
    drain_vmem();
    __syncthreads();
    buf ^= 1;
  }

#pragma unroll
  for (int mt = 0; mt < 4; ++mt) {
#pragma unroll
    for (int nt = 0; nt < 2; ++nt) {
      int col = tileN + wn * 32 + nt * 16 + l16;
      float bcol = bias[col];
      int row0 = tileM + wm * 64 + mt * 16 + lg * 4;
      f32x4 a = acc[mt][nt];
#pragma unroll
      for (int r = 0; r < 4; ++r) {
        int row = row0 + r;
        float v = a[r] + bcol;
        if (MODE == 0) {
          ((__hip_bfloat16*)Cout)[(size_t)row * N + col] = __float2bfloat16(v);
        } else {
          ((float*)Cout)[(size_t)row * N + col] = v;
        }
      }
    }
  }
}

// ---------------- fused QKV projection: XCD-clustered + 3-deep pipeline ----------------
// R11/R16-proven main loop. NEW (R19): V-region blocks bounce the output
// tile through LDS ([cv][kv], row stride 132 = +4 pad) and emit coalesced
// 256B row stores — replaces the 2B-grain 4KB-stride Vt scatter that caused
// ~24MB of HBM RMW fetch (R11 diagnosis; R12's operand-swap fix perturbed
// the main loop and failed — this change is epilogue-only).
__global__ __launch_bounds__(256, 3)
void gemm_qkv(const __hip_bfloat16* __restrict__ decB,
              const __hip_bfloat16* __restrict__ WqB,
              const float* __restrict__ bq,
              const __hip_bfloat16* __restrict__ encB,
              const __hip_bfloat16* __restrict__ WkvB,
              const float* __restrict__ bk,
              const float* __restrict__ bv,
              __hip_bfloat16* __restrict__ Qout,
              __hip_bfloat16* __restrict__ Kout,
              __hip_bfloat16* __restrict__ Vtout,
              const int* __restrict__ vmask) {
  const int K = 1024;
  __shared__ __hip_bfloat16 ls[24576];   // 48KB: 3x8KB A | 3x8KB B; epilogue reuses as [128][132]
  __hip_bfloat16* lAp = ls;              // [3][128*32]
  __hip_bfloat16* lBp = ls + 12288;      // [3][128*32]
  const int tid = threadIdx.x;
  const int lane = tid & 63, wv = tid >> 6;
  const int l16 = lane & 15, lg = lane >> 4;
  const int wm = wv >> 1, wn = wv & 1;

  const int xcd = blockIdx.x & 7;
  const int idx = blockIdx.x >> 3;       // 0..159 within XCD
  const bool isQ = idx < 32;
  int tileM, tileN;
  const __hip_bfloat16 *A, *Bt;
  if (isQ) {
    int qt = xcd * 32 + idx;             // 0..255
    tileM = (qt >> 3) * 128; tileN = (qt & 7) * 128;
    A = decB; Bt = WqB;
  } else {
    int kvt = xcd * 128 + (idx - 32);    // 0..1023
    tileM = (kvt >> 4) * 128; tileN = (kvt & 15) * 128;
    A = encB; Bt = WkvB;
  }
  const int KB = K * 2;

  f32x4 acc[4][4] = {};
  const int o0 = tid * 16;

  auto GSTAGE = [&](int bi, int kt) {
#pragma unroll
    for (int j = 0; j < 2; ++j) {
      int o = o0 + j * 4096;
      int row = o >> 6, col = (o & 63) ^ ((row & 3) << 4);
      gload_lds16((const char*)A + (size_t)(tileM + row) * KB + kt * 2 + col,
                  (char*)(lAp + bi * 4096) + (tid & 192) * 16 + j * 4096);
    }
#pragma unroll
    for (int j = 0; j < 2; ++j) {
      int o = o0 + j * 4096;
      int row = o >> 6, col = (o & 63) ^ ((row & 3) << 4);
      gload_lds16((const char*)Bt + (size_t)(tileN + row) * KB + kt * 2 + col,
                  (char*)(lBp + bi * 4096) + (tid & 192) * 16 + j * 4096);
    }
  };

  GSTAGE(0, 0);
  GSTAGE(1, 32);
  const int NT = K / 32;                 // 32
  for (int t = 0; t < NT; ++t) {
    if (t < NT - 1) {
      asm volatile("s_waitcnt vmcnt(4)" ::: "memory");
    } else {
      asm volatile("s_waitcnt vmcnt(0)" ::: "memory");
    }
    __builtin_amdgcn_sched_barrier(0);
    __syncthreads();
    if (t + 2 < NT) GSTAGE((t + 2) % 3, (t + 2) * 32);

    const int buf = t % 3;
    bf16x8 af[4], bfr[4];
#pragma unroll
    for (int mt = 0; mt < 4; ++mt) {
      const int row = wm * 64 + mt * 16 + l16;
      af[mt] = *(const bf16x8*)((const char*)(lAp + buf * 4096) + row * 64 + ((lg * 16) ^ ((row & 3) << 4)));
    }
#pragma unroll
    for (int nt = 0; nt < 4; ++nt) {
      const int row = wn * 64 + nt * 16 + l16;
      bfr[nt] = *(const bf16x8*)((const char*)(lBp + buf * 4096) + row * 64 + ((lg * 16) ^ ((row & 3) << 4)));
    }
#pragma unroll
    for (int mt = 0; mt < 4; ++mt)
#pragma unroll
      for (int nt = 0; nt < 4; ++nt)
        acc[mt][nt] = __builtin_amdgcn_mfma_f32_16x16x32_bf16(af[mt], bfr[nt], acc[mt][nt], 0, 0, 0);
  }

  if (!isQ && tileN >= 1024) {
    // ---- V region: LDS-bounce epilogue -> coalesced Vt stores ----
    const int b0 = tileM >> 11;
    const int kvb = tileM & 2047;
    const int cvbase = tileN - 1024;
    __syncthreads();                     // all ds_reads of final tile done
#pragma unroll
    for (int mt = 0; mt < 4; ++mt) {
      int kvr0 = wm * 64 + mt * 16 + lg * 4;
#pragma unroll
      for (int nt = 0; nt < 4; ++nt) {
        int cvr = wn * 64 + nt * 16 + l16;
        float bc = bv[cvbase + cvr];
        f32x4 a = acc[mt][nt];
        union { unsigned u2[2]; __hip_bfloat16 h[4]; } pkv;
#pragma unroll
        for (int r = 0; r < 4; ++r) {
          float v = a[r] + bc;
          if (!vmask[b0 * 2048 + kvb + kvr0 + r]) v = 0.0f;
          pkv.h[r] = __float2bfloat16(v);
        }
        *(uint2v*)(ls + cvr * 132 + kvr0) = *(uint2v*)pkv.u2;   // 8B packed, padded stride
      }
    }
    __syncthreads();
#pragma unroll
    for (int p = 0; p < 32; ++p) {
      int row = wv + p * 4;              // cv_rel
      unsigned d = *(const unsigned*)((const char*)ls + row * 264 + lane * 4);
      *(unsigned*)((char*)Vtout + (((size_t)(b0 * 1024 + cvbase + row)) * 2048 + kvb + lane * 2) * 2) = d;
    }
  } else {
#pragma unroll
    for (int mt = 0; mt < 4; ++mt) {
#pragma unroll
      for (int nt = 0; nt < 4; ++nt) {
        int col = tileN + wn * 64 + nt * 16 + l16;
        int row0 = tileM + wm * 64 + mt * 16 + lg * 4;
        f32x4 a = acc[mt][nt];
        if (isQ) {
          float bc = bq[col];
#pragma unroll
          for (int r = 0; r < 4; ++r) {
            int row = row0 + r;
            Qout[(size_t)row * 1024 + col] = __float2bfloat16(a[r] + bc);
          }
        } else {
          float bc = bk[col];
#pragma unroll
          for (int r = 0; r < 4; ++r) {
            int row = row0 + r;
            Kout[(size_t)row * 1024 + col] = __float2bfloat16(a[r] + bc);
          }
        }
      }
    }
  }
}

// ---------------- flash attention, swapped-QK^T 32x32, KVBLK=128 (R14 proven) ----------------
__global__ __launch_bounds__(256, 2)
void attn_fwd(const __hip_bfloat16* __restrict__ Qg,
              const __hip_bfloat16* __restrict__ Kg,
              const __hip_bfloat16* __restrict__ Vt,
              const __hip_bfloat16* __restrict__ mkb,
              __hip_bfloat16* __restrict__ AO) {
  __shared__ __hip_bfloat16 lK[2][128 * 64];
  __shared__ __hip_bfloat16 lV[2][2][64 * 64];
  const int tid = threadIdx.x, lane = tid & 63, wv = tid >> 6;
  const int l32 = lane & 31, h = lane >> 5;

  const int blk = blockIdx.x;
  const int c8 = blk & 7, j = blk >> 3;
  const int g8 = c8 * 8 + (j & 7);   // (b,hd) group, clustered per XCD
  const int qi = j >> 3;
  const int hd = g8 & 15, b = g8 >> 4;
  const int qb = qi * 128;
  const int q0 = qb + wv * 32;

  const char* qbase = (const char*)Qg +
      ((size_t)(b * LQ_ + q0 + l32) * DM_ + hd * DH_ + h * 8) * 2;
  bf16x8 qf[4];
#pragma unroll
  for (int dk = 0; dk < 4; ++dk) qf[dk] = *(const bf16x8*)(qbase + dk * 32);

  f32x16 o_[2] = {};
  f32x16 l_acc = {};
  float m2 = -1e30f;                 // running max, log2 domain
  const float S2 = 0.18033688f;      // 0.125 * 1/ln2
  const __hip_bfloat16* mrow = mkb + b * LKV_;
  const char* Kbase = (const char*)Kg + ((size_t)(b * LKV_) * DM_ + hd * DH_) * 2;
  const char* Vbase = (const char*)Vt + ((size_t)((b * H_ + hd) * DH_)) * LKV_ * 2;

  const int ofs = wv * 1024 + lane * 16;

  auto STAGE = [&](int bi, int kv0) {
#pragma unroll
    for (int r = 0; r < 4; ++r) {
      int o = ofs + r * 4096;
      int row = o >> 7, col = (o & 127) ^ ((row & 7) << 4);
      gload_lds16(Kbase + (size_t)(kv0 + row) * 2048 + col,
                  (char*)lK[bi] + wv * 1024 + r * 4096);
    }
#pragma unroll
    for (int s = 0; s < 2; ++s)
#pragma unroll
      for (int r = 0; r < 2; ++r) {
        int o = ofs + r * 4096;
        int row = o >> 7, col = (o & 127) ^ ((row & 7) << 4);
        gload_lds16(Vbase + (size_t)row * 4096 + (kv0 + s * 64) * 2 + col,
                    (char*)lV[bi][s] + wv * 1024 + r * 4096);
      }
  };

  STAGE(0, 0);
  drain_vmem();
  __syncthreads();
  int buf = 0;

  for (int it = 0; it < LKV_ / 128; ++it) {
    const int kv0 = it * 128;
    if (it + 1 < LKV_ / 128) STAGE(buf ^ 1, kv0 + 128);

    // S^T = K Q^T : col = q = l32 ; row = kv = (g&3)+8*(g>>2)+4*h (+32t)
    f32x16 z[4];
#pragma unroll
    for (int t = 0; t < 4; ++t) {
      z[t] = {};
      const int row = t * 32 + l32;
      const int sw = (row & 7) << 4;
      const char* kp = (const char*)lK[buf] + row * 128;
      __builtin_amdgcn_s_setprio(1);
#pragma unroll
      for (int dk = 0; dk < 4; ++dk) {
        bf16x8 kf = *(const bf16x8*)(kp + ((dk * 32 + h * 16) ^ sw));
        z[t] = __builtin_amdgcn_mfma_f32_32x32x16_bf16(kf, qf[dk], z[t], 0, 0, 0);
      }
      __builtin_amdgcn_s_setprio(0);
    }

    // per-q max over 128 kv: balanced tree, lane-local + one cross-half reduce
    f32x16 zm;
#pragma unroll
    for (int g = 0; g < 16; ++g)
      zm[g] = fmaxf(fmaxf(z[0][g], z[1][g]), fmaxf(z[2][g], z[3][g]));
    float m0 = fmaxf(fmaxf(zm[0], zm[1]), fmaxf(zm[2], zm[3]));
    float m1 = fmaxf(fmaxf(zm[4], zm[5]), fmaxf(zm[6], zm[7]));
    float m4 = fmaxf(fmaxf(zm[8], zm[9]), fmaxf(zm[10], zm[11]));
    float m5 = fmaxf(fmaxf(zm[12], zm[13]), fmaxf(zm[14], zm[15]));
    float mx = fmaxf(fmaxf(m0, m1), fmaxf(m4, m5));
    mx = fmaxf(mx, __shfl_xor(mx, 32));
    float mx2 = mx * S2;

    // T13 defer-max (log2 domain, thr = 8/ln2)
    if (!__all(mx2 - m2 <= 11.5416f)) {
      float mn = fmaxf(m2, mx2);
      float alpha = EXP2(m2 - mn);
      m2 = mn;
#pragma unroll
      for (int g = 0; g < 16; ++g) {
        float a2 = __shfl(alpha, (g & 3) + 8 * (g >> 2) + 4 * h);
        o_[0][g] *= a2;
        o_[1][g] *= a2;
        l_acc[g] *= a2;
      }
    }

    // P = exp2(z*S2 - m2)
    const float negm2 = -m2;
    unsigned pk[4][4][2];
#pragma unroll
    for (int t = 0; t < 4; ++t)
#pragma unroll
      for (int s = 0; s < 4; ++s) {
        float p0 = EXP2(fmaf(z[t][s * 4 + 0], S2, negm2));
        float p1 = EXP2(fmaf(z[t][s * 4 + 1], S2, negm2));
        float p2 = EXP2(fmaf(z[t][s * 4 + 2], S2, negm2));
        float p3 = EXP2(fmaf(z[t][s * 4 + 3], S2, negm2));
        pk[t][s][0] = pack2(p0, p1);
        pk[t][s][1] = pack2(p2, p3);
      }

    // O += P V ; l_acc += P·mask   (8 chunks of 16 kv)
#pragma unroll
    for (int c = 0; c < 8; ++c) {
      const int t = c >> 1, cc = c & 1;
      const int s = c >> 2, cl = c & 3;
      unsigned w0 = pk[t][2 * cc + 0][0], w1 = pk[t][2 * cc + 0][1];
      unsigned w2 = pk[t][2 * cc + 1][0], w3 = pk[t][2 * cc + 1][1];
      xswap(w0, w2);
      xswap(w1, w3);
      union { unsigned w[4]; bf16x8 v; } au;
      au.w[0] = w0; au.w[1] = w1; au.w[2] = w2; au.w[3] = w3;
      bf16x8 mb8 = *(const bf16x8*)(mrow + kv0 + c * 16 + h * 8);
      __builtin_amdgcn_s_setprio(1);
#pragma unroll
      for (int dt = 0; dt < 2; ++dt) {
        const int row = dt * 32 + l32;
        const int sw = (row & 7) << 4;
        bf16x8 vf = *(const bf16x8*)((const char*)lV[buf][s] + row * 128 + ((cl * 32 + h * 16) ^ sw));
        o_[dt] = __builtin_amdgcn_mfma_f32_32x32x16_bf16(au.v, vf, o_[dt], 0, 0, 0);
      }
      l_acc = __builtin_amdgcn_mfma_f32_32x32x16_bf16(au.v, mb8, l_acc, 0, 0, 0);
      __builtin_amdgcn_s_setprio(0);
    }
    drain_vmem();
    __syncthreads();
    buf ^= 1;
  }

  // l_acc[g] = sum_kv P[q(g,h)][kv]*mask[kv] (identical across cols)
#pragma unroll
  for (int dt = 0; dt < 2; ++dt)
#pragma unroll
    for (int g = 0; g < 16; ++g) {
      int q = (g & 3) + 8 * (g >> 2) + 4 * h;
      AO[(size_t)(b * LQ_ + qb + wv * 32 + q) * DM_ + hd * DH_ + dt * 32 + l32] =
          __float2bfloat16(o_[dt][g] / l_acc[g]);
    }
}

// ---------------- launch ----------------
extern "C" void kernel_launch(void* const* d_in, const int* in_sizes, int n_in,
                              void* d_out, int out_size, void* d_ws, size_t ws_size,
                              hipStream_t stream) {
  const float* dec = (const float*)d_in[0];
  const float* enc = (const float*)d_in[1];
  const int*   msk = (const int*)d_in[2];
  const float* Wq = (const float*)d_in[3];
  const float* bq = (const float*)d_in[4];
  const float* Wk = (const float*)d_in[5];
  const float* bk = (const float*)d_in[6];
  const float* Wv = (const float*)d_in[7];
  const float* bv = (const float*)d_in[8];
  const float* Wo = (const float*)d_in[9];
  const float* bo = (const float*)d_in[10];

  char* ws = (char*)d_ws;
  __hip_bfloat16* decB = (__hip_bfloat16*)(ws);
  __hip_bfloat16* encB = (__hip_bfloat16*)(ws + 8388608);
  __hip_bfloat16* WqB  = (__hip_bfloat16*)(ws + 25165824);
  __hip_bfloat16* WkvB = (__hip_bfloat16*)(ws + 27262976);  // [2048][1024] = Wk ; Wv
  __hip_bfloat16* WoB  = (__hip_bfloat16*)(ws + 31457280);
  __hip_bfloat16* Qb   = (__hip_bfloat16*)(ws + 33554432);
  __hip_bfloat16* Kb   = (__hip_bfloat16*)(ws + 41943040);
  __hip_bfloat16* Vtb  = (__hip_bfloat16*)(ws + 58720256);  // [B,H,Dh,Lkv]
  __hip_bfloat16* AO   = (__hip_bfloat16*)(ws + 75497472);
  __hip_bfloat16* mk2  = (__hip_bfloat16*)(ws + 83886080);  // bf16 0/1 mask

  CastArgs ca;
  ca.src[0] = dec; ca.dst[0] = decB;             ca.n[0] = 4096 * 1024;
  ca.src[1] = enc; ca.dst[1] = encB;             ca.n[1] = 8192 * 1024;
  ca.src[2] = Wq;  ca.dst[2] = WqB;              ca.n[2] = 1024 * 1024;
  ca.src[3] = Wk;  ca.dst[3] = WkvB;             ca.n[3] = 1024 * 1024;
  ca.src[4] = Wv;  ca.dst[4] = WkvB + 1048576;   ca.n[4] = 1024 * 1024;
  ca.src[5] = Wo;  ca.dst[5] = WoB;              ca.n[5] = 1024 * 1024;
  ca.msk = msk; ca.mdst = mk2; ca.mn = B_ * LKV_;
  cast_multi<<<dim3(4096, 7), dim3(256), 0, stream>>>(ca);

  gemm_qkv<<<dim3(1280), dim3(256), 0, stream>>>(decB, WqB, bq, encB, WkvB, bk, bv,
                                                 Qb, Kb, Vtb, msk);

  attn_fwd<<<dim3(512), dim3(256), 0, stream>>>(Qb, Kb, Vtb, mk2, AO);

  gemm_bt<2><<<dim3(512), dim3(256), 0, stream>>>(AO, WoB, bo, d_out, 4096, 1024, 1024);
}